// Round 17
// baseline (161.825 us; speedup 1.0000x reference)
//
#include <hip/hip_runtime.h>
#include <hip/hip_bf16.h>

#define D_MODEL 1280
#define NUM_EXPERTS 20
#define HEAD_DIM 64
#define SEQ 1024
#define BATCH 4
#define BS_TOK 4096
#define QKV_N 192
#define QKV_W 3840   // 20 experts * 192, flat qkv row width

typedef __attribute__((ext_vector_type(8))) short short8;
typedef __attribute__((ext_vector_type(4))) float f32x4;
typedef __attribute__((ext_vector_type(16))) float f32x16;
typedef __hip_bfloat16 bf16;

static __device__ __forceinline__ void gload_lds16(const void* g, void* l) {
  __builtin_amdgcn_global_load_lds((const __attribute__((address_space(1))) void*)g,
                                   (__attribute__((address_space(3))) void*)l, 16, 0, 0);
}

// ---------------- router_w [D][E] f32 -> rwT [E][D] f32 ----------------
__global__ __launch_bounds__(256) void k_rwT(const float* __restrict__ in,
                                             float* __restrict__ out) {
  int i = blockIdx.x * 256 + threadIdx.x;
  if (i < D_MODEL * NUM_EXPERTS) {
    int d = i / NUM_EXPERTS, e = i % NUM_EXPERTS;
    out[e * D_MODEL + d] = in[i];
  }
}

// ---------------- router gates + x -> bf16 (4 rows/block, wave per row) ----
__global__ __launch_bounds__(256) void k_gates(const float* __restrict__ x,
    const float* __restrict__ rwT, const float* __restrict__ rb,
    float* __restrict__ gates, bf16* __restrict__ xb)
{
  __shared__ __align__(16) float xs[4][D_MODEL];
  __shared__ float logits[4][NUM_EXPERTS];
  const int r0 = blockIdx.x * 4;
  for (int i = threadIdx.x; i < 4 * (D_MODEL / 2); i += 256) {
    int r = i / (D_MODEL / 2), d2 = (i % (D_MODEL / 2)) * 2;
    float2 v = *(const float2*)(x + (size_t)(r0 + r) * D_MODEL + d2);
    xs[r][d2] = v.x; xs[r][d2 + 1] = v.y;
    __hip_bfloat162 h;
    h.x = __float2bfloat16(v.x); h.y = __float2bfloat16(v.y);
    *(__hip_bfloat162*)(xb + (size_t)(r0 + r) * D_MODEL + d2) = h;
  }
  __syncthreads();
  const int wid = threadIdx.x >> 6, lane = threadIdx.x & 63;
  for (int e = 0; e < NUM_EXPERTS; ++e) {
    float s = 0.f;
    #pragma unroll
    for (int j = 0; j < D_MODEL / 256; ++j) {
      int d = (lane + 64 * j) * 4;
      float4 xv = *(const float4*)&xs[wid][d];
      float4 wv = *(const float4*)&rwT[e * D_MODEL + d];
      s += xv.x * wv.x + xv.y * wv.y + xv.z * wv.z + xv.w * wv.w;
    }
    #pragma unroll
    for (int m = 32; m >= 1; m >>= 1) s += __shfl_xor(s, m);
    if (lane == 0) logits[wid][e] = s + rb[e];
  }
  __syncthreads();
  if (lane < 32) {
    float v = (lane < NUM_EXPERTS) ? logits[wid][lane] : -1e30f;
    float mx = v;
    #pragma unroll
    for (int m = 16; m >= 1; m >>= 1) mx = fmaxf(mx, __shfl_xor(mx, m, 32));
    float p = (lane < NUM_EXPERTS) ? __expf(v - mx) : 0.f;
    float sum = p;
    #pragma unroll
    for (int m = 16; m >= 1; m >>= 1) sum += __shfl_xor(sum, m, 32);
    if (lane < NUM_EXPERTS)
      gates[(size_t)(r0 + wid) * NUM_EXPERTS + lane] = p / sum;
  }
}

// ------- merged transposes: z<20 -> wqkv expert z (1280x192); z==20 -> ow --
__global__ __launch_bounds__(256) void k_transpose2(
    const float* __restrict__ wqkv, bf16* __restrict__ wqkvT,
    const float* __restrict__ ow, bf16* __restrict__ owT)
{
  const int z = blockIdx.z;
  const float* in; bf16* out; int R, C;
  if (z < NUM_EXPERTS) {
    if (blockIdx.x >= 6) return;             // uniform per block
    in = wqkv + (size_t)z * D_MODEL * QKV_N; out = wqkvT + (size_t)z * D_MODEL * QKV_N;
    R = D_MODEL; C = QKV_N;
  } else {
    in = ow; out = owT; R = D_MODEL; C = D_MODEL;
  }
  __shared__ float tile[32][33];
  const int c0 = blockIdx.x * 32, r0 = blockIdx.y * 32;
  const int tx = threadIdx.x, ty = threadIdx.y;  // block (32,8)
  #pragma unroll
  for (int i = 0; i < 4; ++i)
    tile[ty + 8*i][tx] = in[(size_t)(r0 + ty + 8*i) * C + (c0 + tx)];
  __syncthreads();
  #pragma unroll
  for (int i = 0; i < 4; ++i)
    out[(size_t)(c0 + ty + 8*i) * R + (r0 + tx)] =
        __float2bfloat16(tile[tx][ty + 8*i]);
}

// ======= 128x128 GEMM, BK=32, 4-deep ring, counted vmcnt, 64KB LDS ========
// 2 blocks/CU -> cross-block MFMA covers barrier drains (m114 overlap).
// Swizzle (64B rows): S(row)=(row>>1)&3 both-sides. Templated output dtype.
// Used for BOTH the QKV GEMM (960 blocks, bf16 out) and out-proj (320, f32).
template<bool OUT_BF16, int NPAN>
__global__ __launch_bounds__(512, 2) void k_gemm128r(
    const bf16* __restrict__ A, const bf16* __restrict__ BT,
    const float* __restrict__ bias, void* __restrict__ C,
    int M, int N, int K)
{
  __shared__ __align__(16) bf16 lds[4][2][128 * 32];
  const int bid = blockIdx.x;
  const int xcd = bid & 7, c = bid >> 3;        // 8 * (4m x NPAN n)
  const int m0 = (xcd * 4 + (c & 3)) * 128;     // 32 m-panels
  const int n0 = (c >> 2) * 128;                // NPAN n-panels
  const int tid = threadIdx.x, wid = tid >> 6, lane = tid & 63;
  const int wr = wid >> 2, wcn = wid & 3;
  const int fr = lane & 15, fg = lane >> 4;
  const int nt = K / 32;                        // 40 K-tiles

  auto STAGE = [&](int t, int buf) {
    const bf16* Ag = A + (size_t)m0 * K + t * 32;
    const bf16* Bg = BT + (size_t)n0 * K + t * 32;
    int row = tid >> 2, sc = tid & 3;
    int g = sc ^ ((row >> 1) & 3);
    gload_lds16(Ag + (size_t)row * K + g * 8, &lds[buf][0][tid * 8]);
    gload_lds16(Bg + (size_t)row * K + g * 8, &lds[buf][1][tid * 8]);
  };

  f32x4 acc[4][2] = {};
  auto COMPUTE = [&](int buf) {
    const bf16* As_ = &lds[buf][0][0];
    const bf16* Bs_ = &lds[buf][1][0];
    short8 af[4], bfv[2];
    #pragma unroll
    for (int mi = 0; mi < 4; ++mi) {
      int row = wr * 64 + mi * 16 + fr;
      int slot = fg ^ ((row >> 1) & 3);
      af[mi] = *(const short8*)(As_ + row * 32 + slot * 8);
    }
    #pragma unroll
    for (int ni = 0; ni < 2; ++ni) {
      int row = wcn * 32 + ni * 16 + fr;
      int slot = fg ^ ((row >> 1) & 3);
      bfv[ni] = *(const short8*)(Bs_ + row * 32 + slot * 8);
    }
    __builtin_amdgcn_s_setprio(1);
    #pragma unroll
    for (int mi = 0; mi < 4; ++mi) {
      #pragma unroll
      for (int ni = 0; ni < 2; ++ni)
        acc[mi][ni] = __builtin_amdgcn_mfma_f32_16x16x32_bf16(
            af[mi], bfv[ni], acc[mi][ni], 0, 0, 0);
    }
    __builtin_amdgcn_s_setprio(0);
  };

  STAGE(0, 0); STAGE(1, 1); STAGE(2, 2);
  asm volatile("s_waitcnt vmcnt(4)" ::: "memory");
  __builtin_amdgcn_s_barrier();
  __builtin_amdgcn_sched_barrier(0);
  int buf = 0;
  for (int t = 0; t < nt - 3; ++t) {
    int nb = buf + 3; nb = (nb >= 4) ? nb - 4 : nb;
    STAGE(t + 3, nb);
    COMPUTE(buf);
    asm volatile("s_waitcnt vmcnt(4)" ::: "memory");   // t+1 complete
    __builtin_amdgcn_s_barrier();
    __builtin_amdgcn_sched_barrier(0);
    buf = (buf == 3) ? 0 : buf + 1;
  }
  COMPUTE(buf);                                        // t = nt-3
  asm volatile("s_waitcnt vmcnt(2)" ::: "memory");
  __builtin_amdgcn_s_barrier();
  __builtin_amdgcn_sched_barrier(0);
  buf = (buf == 3) ? 0 : buf + 1;
  COMPUTE(buf);                                        // t = nt-2
  asm volatile("s_waitcnt vmcnt(0)" ::: "memory");
  __builtin_amdgcn_s_barrier();
  __builtin_amdgcn_sched_barrier(0);
  buf = (buf == 3) ? 0 : buf + 1;
  COMPUTE(buf);                                        // t = nt-1

  #pragma unroll
  for (int mi = 0; mi < 4; ++mi) {
    const int gr = m0 + wr * 64 + mi * 16 + fg * 4;
    #pragma unroll
    for (int ni = 0; ni < 2; ++ni) {
      const int gc = n0 + wcn * 32 + ni * 16 + fr;
      const float bv = bias[gc];
      #pragma unroll
      for (int r = 0; r < 4; ++r) {
        float v = acc[mi][ni][r] + bv;
        size_t off = (size_t)(gr + r) * N + gc;
        if constexpr (OUT_BF16) ((bf16*)C)[off] = __float2bfloat16(v);
        else                    ((float*)C)[off] = v;
      }
    }
  }
}

// ---------------- flash attention, QBLK=64, key-split, no-max --------------
// V-transpose writes packed as b32 key-pairs: thread (vkp=tid>>3, vq4=tid&7)
// covers keys {2vkp,2vkp+1} x h=vq4*8+j, j=0..7 -> full 64x64 tile.
// Swizzle: stored chunk = logical ^ S(row), S(r)=((r>>3)^r)&7.
__global__ __launch_bounds__(256, 4) void k_attn(
    const bf16* __restrict__ qkv, const float* __restrict__ gates,
    bf16* __restrict__ combined)
{
  __shared__ __align__(16) bf16 Ks[2][64 * 64];
  __shared__ __align__(16) bf16 VTs[64 * 64];
  __shared__ float Ltab[64];
  const int id = blockIdx.x;                 // 1280 blocks
  const int xcd = id & 7, kgrp = id >> 3;    // kgrp 0..159
  const int qt = kgrp / 10, bel = kgrp - qt * 10;
  const int be = xcd * 10 + bel;
  const int e = be >> 2, b = be & 3;
  const int s0 = qt * 64;
  const int tid = threadIdx.x, wid = tid >> 6, lane = tid & 63;
  const int l31 = lane & 31, hi = lane >> 5;
  const int qw = wid & 1, kh = wid >> 1;     // q sub-block, key half
  const bf16* base = qkv + (size_t)(b * SEQ) * QKV_W + e * QKV_N;
  const int rq = s0 + qw * 32 + l31;
  short8 qf[4];
  #pragma unroll
  for (int kc = 0; kc < 4; ++kc)
    qf[kc] = *(const short8*)(base + (size_t)rq * QKV_W + kc*16 + hi*8);
  f32x16 o0 = {}, o1 = {};
  float Lr = 0.f;
  const float CSC = 0.125f * 1.44269504f;    // SCALE * log2(e)

  const int kst_row = (lane >> 3);
  const int vkp = tid >> 3, vq4 = tid & 7;   // V map: key pair, h octet
  short8 vrega, vregb;
  auto KSTAGE = [&](int c0, int bsel) {
    #pragma unroll
    for (int p = 0; p < 2; ++p) {
      int W = p*4 + wid;
      int row = W*8 + kst_row;
      int g = (lane & 7) ^ W ^ kst_row;      // chunk ^ S(row)
      gload_lds16(base + (size_t)(c0 + row)*QKV_W + 64 + g*8,
                  &Ks[bsel][(W*64 + lane)*8]);
    }
  };
  auto VLOAD = [&](int c0) {
    vrega = *(const short8*)(base + (size_t)(c0 + 2*vkp)*QKV_W + 128 + vq4*8);
    vregb = *(const short8*)(base + (size_t)(c0 + 2*vkp + 1)*QKV_W + 128 + vq4*8);
  };
  auto VWRITE = [&]() {
    const int kc_ = (2*vkp) >> 3, ko0 = (2*vkp) & 7;   // ko0 even
    #pragma unroll
    for (int j = 0; j < 8; ++j) {
      int h = vq4*8 + j;
      int sc = kc_ ^ (vq4 ^ j);              // kc ^ S(h), S(h)=((h>>3)^h)&7
      unsigned int pk = ((unsigned short)vrega[j]) |
                        (((unsigned int)(unsigned short)vregb[j]) << 16);
      *(unsigned int*)&VTs[h*64 + sc*8 + ko0] = pk;
    }
  };

  KSTAGE(0, 0); VLOAD(0);
  int bsel = 0;
  const int krow = kh*32 + l31;
  const int Sk = ((krow >> 3) ^ krow) & 7;
  for (int t = 0; t < SEQ / 64; ++t) {
    if (t) __syncthreads();                  // sync1: PV(t-1) readers done
    VWRITE();
    __syncthreads();                         // sync2: V visible + K(t) DMA done
    if (t < SEQ / 64 - 1) { KSTAGE((t + 1) * 64, bsel ^ 1); VLOAD((t + 1) * 64); }
    // --- QK^T swapped (this wave's 32 keys x its 32 q) ---
    f32x16 sc = {};
    __builtin_amdgcn_s_setprio(1);
    #pragma unroll
    for (int kc = 0; kc < 4; ++kc) {
      int st = (kc*2 + hi) ^ Sk;
      short8 kf = *(const short8*)(&Ks[bsel][krow*64 + st*8]);
      sc = __builtin_amdgcn_mfma_f32_32x32x16_bf16(kf, qf[kc], sc, 0, 0, 0);
    }
    __builtin_amdgcn_s_setprio(0);
    // --- no-max softmax: p = exp2(sc*CSC), L += sum ---
    float p[16]; float ls = 0.f;
    #pragma unroll
    for (int i = 0; i < 16; ++i) { p[i] = exp2f(sc[i]*CSC); ls += p[i]; }
    Lr += ls + __shfl_xor(ls, 32);
    // --- pack P -> PV A-frags ---
    union { int w[4]; short8 v; } pf0, pf1;
    int ta, tb;
    asm("v_cvt_pk_bf16_f32 %0, %1, %2" : "=v"(ta) : "v"(p[0]), "v"(p[1]));
    asm("v_cvt_pk_bf16_f32 %0, %1, %2" : "=v"(tb) : "v"(p[4]), "v"(p[5]));
    asm volatile("v_permlane32_swap_b32 %0, %1" : "+v"(ta), "+v"(tb));
    pf0.w[0] = ta; pf0.w[2] = tb;
    asm("v_cvt_pk_bf16_f32 %0, %1, %2" : "=v"(ta) : "v"(p[2]), "v"(p[3]));
    asm("v_cvt_pk_bf16_f32 %0, %1, %2" : "=v"(tb) : "v"(p[6]), "v"(p[7]));
    asm volatile("v_permlane32_swap_b32 %0, %1" : "+v"(ta), "+v"(tb));
    pf0.w[1] = ta; pf0.w[3] = tb;
    asm("v_cvt_pk_bf16_f32 %0, %1, %2" : "=v"(ta) : "v"(p[8]), "v"(p[9]));
    asm("v_cvt_pk_bf16_f32 %0, %1, %2" : "=v"(tb) : "v"(p[12]), "v"(p[13]));
    asm volatile("v_permlane32_swap_b32 %0, %1" : "+v"(ta), "+v"(tb));
    pf1.w[0] = ta; pf1.w[2] = tb;
    asm("v_cvt_pk_bf16_f32 %0, %1, %2" : "=v"(ta) : "v"(p[10]), "v"(p[11]));
    asm("v_cvt_pk_bf16_f32 %0, %1, %2" : "=v"(tb) : "v"(p[14]), "v"(p[15]));
    asm volatile("v_permlane32_swap_b32 %0, %1" : "+v"(ta), "+v"(tb));
    pf1.w[1] = ta; pf1.w[3] = tb;
    // --- PV over this wave's key half ---
    __builtin_amdgcn_s_setprio(1);
    #pragma unroll
    for (int kb = 0; kb < 2; ++kb) {
      const short8 pv = (kb == 0) ? pf0.v : pf1.v;
      #pragma unroll
      for (int hb = 0; hb < 2; ++hb) {
        int h = hb*32 + l31;
        int cc = (kh*4 + kb*2 + hi) ^ (((h >> 3) ^ h) & 7);
        short8 vf = *(const short8*)(&VTs[h*64 + cc*8]);
        if (hb == 0) o0 = __builtin_amdgcn_mfma_f32_32x32x16_bf16(pv, vf, o0, 0, 0, 0);
        else         o1 = __builtin_amdgcn_mfma_f32_32x32x16_bf16(pv, vf, o1, 0, 0, 0);
      }
    }
    __builtin_amdgcn_s_setprio(0);
    bsel ^= 1;
  }
  // --- cross-wave combine: (qw,kh=1) partials -> (qw,kh=0) waves ---
  __syncthreads();                           // all compute done; LDS reusable
  float* Ops = (float*)&Ks[0][0];            // [64][64] f32 = 16 KB
  float* Lp  = (float*)&VTs[0];              // [64] f32
  if (kh == 1) {
    #pragma unroll
    for (int reg = 0; reg < 16; ++reg) {
      int crow = (reg & 3) + 8*(reg >> 2) + 4*hi;
      Ops[(qw*32 + crow)*64 + l31]      = o0[reg];
      Ops[(qw*32 + crow)*64 + 32 + l31] = o1[reg];
    }
    if (lane < 32) Lp[qw*32 + lane] = Lr;
  }
  __syncthreads();
  if (kh == 0) {
    #pragma unroll
    for (int reg = 0; reg < 16; ++reg) {
      int crow = (reg & 3) + 8*(reg >> 2) + 4*hi;
      o0[reg] += Ops[(qw*32 + crow)*64 + l31];
      o1[reg] += Ops[(qw*32 + crow)*64 + 32 + l31];
    }
    if (lane < 32) {
      float Lt = Lr + Lp[qw*32 + lane];
      float g = gates[(size_t)(b*SEQ + s0 + qw*32 + lane) * NUM_EXPERTS + e];
      Ltab[qw*32 + lane] = g / Lt;
    }
    const int rowbase = b*SEQ + s0 + qw*32;
    #pragma unroll
    for (int reg = 0; reg < 16; ++reg) {
      int crow = (reg & 3) + 8*(reg >> 2) + 4*hi;
      float inv = Ltab[qw*32 + crow];
      combined[(size_t)(rowbase + crow)*D_MODEL + e*64 + l31] =
          __float2bfloat16(o0[reg] * inv);
      combined[(size_t)(rowbase + crow)*D_MODEL + e*64 + 32 + l31] =
          __float2bfloat16(o1[reg] * inv);
    }
  }
}

extern "C" void kernel_launch(void* const* d_in, const int* in_sizes, int n_in,
                              void* d_out, int out_size, void* d_ws, size_t ws_size,
                              hipStream_t stream) {
  const float* x    = (const float*)d_in[0];
  const float* wqkv = (const float*)d_in[1];
  const float* bqkv = (const float*)d_in[2];
  const float* rw   = (const float*)d_in[3];
  const float* rb   = (const float*)d_in[4];
  const float* ow   = (const float*)d_in[5];
  const float* ob   = (const float*)d_in[6];
  char* ws = (char*)d_ws;
  bf16*  xb    = (bf16*)(ws);                    // 4096*1280*2      = 10485760
  bf16*  wqkvT = (bf16*)(ws + 10485760);         // [3840][1280] bf16=  9830400
  bf16*  owT   = (bf16*)(ws + 20316160);         // 1280*1280*2     =  3276800
  float* gates = (float*)(ws + 23592960);        // 4096*20*4       =   327680
  bf16*  qkv   = (bf16*)(ws + 23920640);         // [4096][3840] bf16= 31457280
  bf16*  comb  = (bf16*)(ws + 55377920);         // 4096*1280*2     = 10485760
  float* rwT   = (float*)comb;                   // aliased, consumed pre-attn

  k_rwT<<<(D_MODEL * NUM_EXPERTS + 255) / 256, 256, 0, stream>>>(rw, rwT);
  k_gates<<<1024, 256, 0, stream>>>(x, rwT, rb, gates, xb);
  k_transpose2<<<dim3(40, 40, 21), dim3(32, 8), 0, stream>>>(wqkv, wqkvT, ow, owT);
  // QKV GEMM on the 128^2 ring template: 960 = 8 xcd * (4 m * 30 n), 2 blk/CU
  k_gemm128r<true, 30><<<960, 512, 0, stream>>>(xb, wqkvT, bqkv, qkv,
                                                BS_TOK, QKV_W, D_MODEL);
  k_attn<<<1280, 256, 0, stream>>>(qkv, gates, comb);
  k_gemm128r<false, 10><<<320, 512, 0, stream>>>(comb, owT, ob, d_out,
                                                 BS_TOK, D_MODEL, D_MODEL);
}

// Round 18
// 153.691 us; speedup vs baseline: 1.0529x; 1.0529x over previous
//
#include <hip/hip_runtime.h>
#include <hip/hip_bf16.h>

#define D_MODEL 1280
#define NUM_EXPERTS 20
#define HEAD_DIM 64
#define SEQ 1024
#define BATCH 4
#define BS_TOK 4096
#define QKV_N 192
#define QKV_W 3840   // 20 experts * 192, flat qkv row width

typedef __attribute__((ext_vector_type(8))) short short8;
typedef __attribute__((ext_vector_type(4))) float f32x4;
typedef __attribute__((ext_vector_type(16))) float f32x16;
typedef __hip_bfloat16 bf16;

static __device__ __forceinline__ void gload_lds16(const void* g, void* l) {
  __builtin_amdgcn_global_load_lds((const __attribute__((address_space(1))) void*)g,
                                   (__attribute__((address_space(3))) void*)l, 16, 0, 0);
}

// ---------------- router_w [D][E] f32 -> rwT [E][D] f32 ----------------
__global__ __launch_bounds__(256) void k_rwT(const float* __restrict__ in,
                                             float* __restrict__ out) {
  int i = blockIdx.x * 256 + threadIdx.x;
  if (i < D_MODEL * NUM_EXPERTS) {
    int d = i / NUM_EXPERTS, e = i % NUM_EXPERTS;
    out[e * D_MODEL + d] = in[i];
  }
}

// ---------------- router gates + x -> bf16 (4 rows/block, wave per row) ----
__global__ __launch_bounds__(256) void k_gates(const float* __restrict__ x,
    const float* __restrict__ rwT, const float* __restrict__ rb,
    float* __restrict__ gates, bf16* __restrict__ xb)
{
  __shared__ __align__(16) float xs[4][D_MODEL];
  __shared__ float logits[4][NUM_EXPERTS];
  const int r0 = blockIdx.x * 4;
  for (int i = threadIdx.x; i < 4 * (D_MODEL / 2); i += 256) {
    int r = i / (D_MODEL / 2), d2 = (i % (D_MODEL / 2)) * 2;
    float2 v = *(const float2*)(x + (size_t)(r0 + r) * D_MODEL + d2);
    xs[r][d2] = v.x; xs[r][d2 + 1] = v.y;
    __hip_bfloat162 h;
    h.x = __float2bfloat16(v.x); h.y = __float2bfloat16(v.y);
    *(__hip_bfloat162*)(xb + (size_t)(r0 + r) * D_MODEL + d2) = h;
  }
  __syncthreads();
  const int wid = threadIdx.x >> 6, lane = threadIdx.x & 63;
  for (int e = 0; e < NUM_EXPERTS; ++e) {
    float s = 0.f;
    #pragma unroll
    for (int j = 0; j < D_MODEL / 256; ++j) {
      int d = (lane + 64 * j) * 4;
      float4 xv = *(const float4*)&xs[wid][d];
      float4 wv = *(const float4*)&rwT[e * D_MODEL + d];
      s += xv.x * wv.x + xv.y * wv.y + xv.z * wv.z + xv.w * wv.w;
    }
    #pragma unroll
    for (int m = 32; m >= 1; m >>= 1) s += __shfl_xor(s, m);
    if (lane == 0) logits[wid][e] = s + rb[e];
  }
  __syncthreads();
  if (lane < 32) {
    float v = (lane < NUM_EXPERTS) ? logits[wid][lane] : -1e30f;
    float mx = v;
    #pragma unroll
    for (int m = 16; m >= 1; m >>= 1) mx = fmaxf(mx, __shfl_xor(mx, m, 32));
    float p = (lane < NUM_EXPERTS) ? __expf(v - mx) : 0.f;
    float sum = p;
    #pragma unroll
    for (int m = 16; m >= 1; m >>= 1) sum += __shfl_xor(sum, m, 32);
    if (lane < NUM_EXPERTS)
      gates[(size_t)(r0 + wid) * NUM_EXPERTS + lane] = p / sum;
  }
}

// ------- merged transposes: z<20 -> wqkv expert z (1280x192); z==20 -> ow --
__global__ __launch_bounds__(256) void k_transpose2(
    const float* __restrict__ wqkv, bf16* __restrict__ wqkvT,
    const float* __restrict__ ow, bf16* __restrict__ owT)
{
  const int z = blockIdx.z;
  const float* in; bf16* out; int R, C;
  if (z < NUM_EXPERTS) {
    if (blockIdx.x >= 6) return;             // uniform per block
    in = wqkv + (size_t)z * D_MODEL * QKV_N; out = wqkvT + (size_t)z * D_MODEL * QKV_N;
    R = D_MODEL; C = QKV_N;
  } else {
    in = ow; out = owT; R = D_MODEL; C = D_MODEL;
  }
  __shared__ float tile[32][33];
  const int c0 = blockIdx.x * 32, r0 = blockIdx.y * 32;
  const int tx = threadIdx.x, ty = threadIdx.y;  // block (32,8)
  #pragma unroll
  for (int i = 0; i < 4; ++i)
    tile[ty + 8*i][tx] = in[(size_t)(r0 + ty + 8*i) * C + (c0 + tx)];
  __syncthreads();
  #pragma unroll
  for (int i = 0; i < 4; ++i)
    out[(size_t)(c0 + ty + 8*i) * R + (r0 + tx)] =
        __float2bfloat16(tile[tx][ty + 8*i]);
}

// ======= 256x256 bf16 GEMM, BK=32, 4-deep LDS ring, counted vmcnt =========
// R13/R16 measured-best form. Swizzle (64B rows): S(row)=(row>>1)&3.
__global__ __launch_bounds__(512, 2) void k_gemm256(
    const bf16* __restrict__ A, const bf16* __restrict__ BT,
    const float* __restrict__ bias, bf16* __restrict__ C,
    int M, int N, int K)
{
  __shared__ __align__(16) bf16 lds[4][2][256 * 32];
  const int bid = blockIdx.x;
  const int xcd = bid & 7, c = bid >> 3;        // 240 = 8 * 30
  const int m0 = (xcd * 2 + (c & 1)) * 256;     // 16 m-panels
  const int n0 = (c >> 1) * 256;                // 15 n-panels
  const int tid = threadIdx.x, wid = tid >> 6, lane = tid & 63;
  const int wr = wid >> 2, wcn = wid & 3;
  const int fr = lane & 15, fg = lane >> 4;
  const int nt = K / 32;                        // 40 K-tiles

  auto STAGE = [&](int t, int buf) {
    const bf16* Ag = A + (size_t)m0 * K + t * 32;
    const bf16* Bg = BT + (size_t)n0 * K + t * 32;
    #pragma unroll
    for (int i = 0; i < 2; ++i) {
      int idx = i * 512 + tid;
      int row = idx >> 2, sc = idx & 3;
      int g = sc ^ ((row >> 1) & 3);
      gload_lds16(Ag + (size_t)row * K + g * 8, &lds[buf][0][idx * 8]);
    }
    #pragma unroll
    for (int i = 0; i < 2; ++i) {
      int idx = i * 512 + tid;
      int row = idx >> 2, sc = idx & 3;
      int g = sc ^ ((row >> 1) & 3);
      gload_lds16(Bg + (size_t)row * K + g * 8, &lds[buf][1][idx * 8]);
    }
  };

  f32x4 acc[8][4] = {};
  auto COMPUTE = [&](int buf) {
    const bf16* As_ = &lds[buf][0][0];
    const bf16* Bs_ = &lds[buf][1][0];
    short8 af[8], bfv[4];
    #pragma unroll
    for (int mi = 0; mi < 8; ++mi) {
      int row = wr * 128 + mi * 16 + fr;
      int slot = fg ^ ((row >> 1) & 3);
      af[mi] = *(const short8*)(As_ + row * 32 + slot * 8);
    }
    #pragma unroll
    for (int ni = 0; ni < 4; ++ni) {
      int row = wcn * 64 + ni * 16 + fr;
      int slot = fg ^ ((row >> 1) & 3);
      bfv[ni] = *(const short8*)(Bs_ + row * 32 + slot * 8);
    }
    __builtin_amdgcn_s_setprio(1);
    #pragma unroll
    for (int mi = 0; mi < 8; ++mi) {
      #pragma unroll
      for (int ni = 0; ni < 4; ++ni)
        acc[mi][ni] = __builtin_amdgcn_mfma_f32_16x16x32_bf16(
            af[mi], bfv[ni], acc[mi][ni], 0, 0, 0);
    }
    __builtin_amdgcn_s_setprio(0);
  };

  STAGE(0, 0); STAGE(1, 1); STAGE(2, 2);
  asm volatile("s_waitcnt vmcnt(8)" ::: "memory");
  __builtin_amdgcn_s_barrier();
  __builtin_amdgcn_sched_barrier(0);
  int buf = 0;
  for (int t = 0; t < nt - 3; ++t) {
    int nb = buf + 3; nb = (nb >= 4) ? nb - 4 : nb;
    STAGE(t + 3, nb);
    COMPUTE(buf);
    asm volatile("s_waitcnt vmcnt(8)" ::: "memory");   // t+1 complete
    __builtin_amdgcn_s_barrier();
    __builtin_amdgcn_sched_barrier(0);
    buf = (buf == 3) ? 0 : buf + 1;
  }
  COMPUTE(buf);                                        // t = nt-3
  asm volatile("s_waitcnt vmcnt(4)" ::: "memory");
  __builtin_amdgcn_s_barrier();
  __builtin_amdgcn_sched_barrier(0);
  buf = (buf == 3) ? 0 : buf + 1;
  COMPUTE(buf);                                        // t = nt-2
  asm volatile("s_waitcnt vmcnt(0)" ::: "memory");
  __builtin_amdgcn_s_barrier();
  __builtin_amdgcn_sched_barrier(0);
  buf = (buf == 3) ? 0 : buf + 1;
  COMPUTE(buf);                                        // t = nt-1

  #pragma unroll
  for (int mi = 0; mi < 8; ++mi) {
    const int gr = m0 + wr * 128 + mi * 16 + fg * 4;
    #pragma unroll
    for (int ni = 0; ni < 4; ++ni) {
      const int gc = n0 + wcn * 64 + ni * 16 + fr;
      const float bv = bias[gc];
      #pragma unroll
      for (int r = 0; r < 4; ++r)
        C[(size_t)(gr + r) * N + gc] = __float2bfloat16(acc[mi][ni][r] + bv);
    }
  }
}

// ======= 128x128 f32-out GEMM, BK=32, 4-deep ring, counted vmcnt ==========
__global__ __launch_bounds__(512, 2) void k_gemm128r(
    const bf16* __restrict__ A, const bf16* __restrict__ BT,
    const float* __restrict__ bias, float* __restrict__ C,
    int M, int N, int K)
{
  __shared__ __align__(16) bf16 lds[4][2][128 * 32];
  const int bid = blockIdx.x;
  const int xcd = bid & 7, c = bid >> 3;        // 320 = 8 * 40
  const int m0 = (xcd * 4 + (c & 3)) * 128;     // 32 m-panels
  const int n0 = (c >> 2) * 128;                // 10 n-panels
  const int tid = threadIdx.x, wid = tid >> 6, lane = tid & 63;
  const int wr = wid >> 2, wcn = wid & 3;
  const int fr = lane & 15, fg = lane >> 4;
  const int nt = K / 32;                        // 40 K-tiles

  auto STAGE = [&](int t, int buf) {
    const bf16* Ag = A + (size_t)m0 * K + t * 32;
    const bf16* Bg = BT + (size_t)n0 * K + t * 32;
    int row = tid >> 2, sc = tid & 3;
    int g = sc ^ ((row >> 1) & 3);
    gload_lds16(Ag + (size_t)row * K + g * 8, &lds[buf][0][tid * 8]);
    gload_lds16(Bg + (size_t)row * K + g * 8, &lds[buf][1][tid * 8]);
  };

  f32x4 acc[4][2] = {};
  auto COMPUTE = [&](int buf) {
    const bf16* As_ = &lds[buf][0][0];
    const bf16* Bs_ = &lds[buf][1][0];
    short8 af[4], bfv[2];
    #pragma unroll
    for (int mi = 0; mi < 4; ++mi) {
      int row = wr * 64 + mi * 16 + fr;
      int slot = fg ^ ((row >> 1) & 3);
      af[mi] = *(const short8*)(As_ + row * 32 + slot * 8);
    }
    #pragma unroll
    for (int ni = 0; ni < 2; ++ni) {
      int row = wcn * 32 + ni * 16 + fr;
      int slot = fg ^ ((row >> 1) & 3);
      bfv[ni] = *(const short8*)(Bs_ + row * 32 + slot * 8);
    }
    __builtin_amdgcn_s_setprio(1);
    #pragma unroll
    for (int mi = 0; mi < 4; ++mi) {
      #pragma unroll
      for (int ni = 0; ni < 2; ++ni)
        acc[mi][ni] = __builtin_amdgcn_mfma_f32_16x16x32_bf16(
            af[mi], bfv[ni], acc[mi][ni], 0, 0, 0);
    }
    __builtin_amdgcn_s_setprio(0);
  };

  STAGE(0, 0); STAGE(1, 1); STAGE(2, 2);
  asm volatile("s_waitcnt vmcnt(4)" ::: "memory");
  __builtin_amdgcn_s_barrier();
  __builtin_amdgcn_sched_barrier(0);
  int buf = 0;
  for (int t = 0; t < nt - 3; ++t) {
    int nb = buf + 3; nb = (nb >= 4) ? nb - 4 : nb;
    STAGE(t + 3, nb);
    COMPUTE(buf);
    asm volatile("s_waitcnt vmcnt(4)" ::: "memory");   // t+1 complete
    __builtin_amdgcn_s_barrier();
    __builtin_amdgcn_sched_barrier(0);
    buf = (buf == 3) ? 0 : buf + 1;
  }
  COMPUTE(buf);                                        // t = nt-3
  asm volatile("s_waitcnt vmcnt(2)" ::: "memory");
  __builtin_amdgcn_s_barrier();
  __builtin_amdgcn_sched_barrier(0);
  buf = (buf == 3) ? 0 : buf + 1;
  COMPUTE(buf);                                        // t = nt-2
  asm volatile("s_waitcnt vmcnt(0)" ::: "memory");
  __builtin_amdgcn_s_barrier();
  __builtin_amdgcn_sched_barrier(0);
  buf = (buf == 3) ? 0 : buf + 1;
  COMPUTE(buf);                                        // t = nt-1

  #pragma unroll
  for (int mi = 0; mi < 4; ++mi) {
    const int gr = m0 + wr * 64 + mi * 16 + fg * 4;
    #pragma unroll
    for (int ni = 0; ni < 2; ++ni) {
      const int gc = n0 + wcn * 32 + ni * 16 + fr;
      const float bv = bias[gc];
      #pragma unroll
      for (int r = 0; r < 4; ++r)
        C[(size_t)(gr + r) * N + gc] = acc[mi][ni][r] + bv;
    }
  }
}

// ---------------- flash attention, QBLK=64, key-split, no-max --------------
// V-transpose writes packed as b32 key-pairs: thread (vkp=tid>>3, vq4=tid&7)
// covers keys {2vkp,2vkp+1} x h=vq4*8+j, j=0..7 -> full 64x64 tile.
// Swizzle: stored chunk = logical ^ S(row), S(r)=((r>>3)^r)&7.
__global__ __launch_bounds__(256, 4) void k_attn(
    const bf16* __restrict__ qkv, const float* __restrict__ gates,
    bf16* __restrict__ combined)
{
  __shared__ __align__(16) bf16 Ks[2][64 * 64];
  __shared__ __align__(16) bf16 VTs[64 * 64];
  __shared__ float Ltab[64];
  const int id = blockIdx.x;                 // 1280 blocks
  const int xcd = id & 7, kgrp = id >> 3;    // kgrp 0..159
  const int qt = kgrp / 10, bel = kgrp - qt * 10;
  const int be = xcd * 10 + bel;
  const int e = be >> 2, b = be & 3;
  const int s0 = qt * 64;
  const int tid = threadIdx.x, wid = tid >> 6, lane = tid & 63;
  const int l31 = lane & 31, hi = lane >> 5;
  const int qw = wid & 1, kh = wid >> 1;     // q sub-block, key half
  const bf16* base = qkv + (size_t)(b * SEQ) * QKV_W + e * QKV_N;
  const int rq = s0 + qw * 32 + l31;
  short8 qf[4];
  #pragma unroll
  for (int kc = 0; kc < 4; ++kc)
    qf[kc] = *(const short8*)(base + (size_t)rq * QKV_W + kc*16 + hi*8);
  f32x16 o0 = {}, o1 = {};
  float Lr = 0.f;
  const float CSC = 0.125f * 1.44269504f;    // SCALE * log2(e)

  const int kst_row = (lane >> 3);
  const int vkp = tid >> 3, vq4 = tid & 7;   // V map: key pair, h octet
  short8 vrega, vregb;
  auto KSTAGE = [&](int c0, int bsel) {
    #pragma unroll
    for (int p = 0; p < 2; ++p) {
      int W = p*4 + wid;
      int row = W*8 + kst_row;
      int g = (lane & 7) ^ W ^ kst_row;      // chunk ^ S(row)
      gload_lds16(base + (size_t)(c0 + row)*QKV_W + 64 + g*8,
                  &Ks[bsel][(W*64 + lane)*8]);
    }
  };
  auto VLOAD = [&](int c0) {
    vrega = *(const short8*)(base + (size_t)(c0 + 2*vkp)*QKV_W + 128 + vq4*8);
    vregb = *(const short8*)(base + (size_t)(c0 + 2*vkp + 1)*QKV_W + 128 + vq4*8);
  };
  auto VWRITE = [&]() {
    const int kc_ = (2*vkp) >> 3, ko0 = (2*vkp) & 7;   // ko0 even
    #pragma unroll
    for (int j = 0; j < 8; ++j) {
      int h = vq4*8 + j;
      int sc = kc_ ^ (vq4 ^ j);              // kc ^ S(h), S(h)=((h>>3)^h)&7
      unsigned int pk = ((unsigned short)vrega[j]) |
                        (((unsigned int)(unsigned short)vregb[j]) << 16);
      *(unsigned int*)&VTs[h*64 + sc*8 + ko0] = pk;
    }
  };

  KSTAGE(0, 0); VLOAD(0);
  int bsel = 0;
  const int krow = kh*32 + l31;
  const int Sk = ((krow >> 3) ^ krow) & 7;
  for (int t = 0; t < SEQ / 64; ++t) {
    if (t) __syncthreads();                  // sync1: PV(t-1) readers done
    VWRITE();
    __syncthreads();                         // sync2: V visible + K(t) DMA done
    if (t < SEQ / 64 - 1) { KSTAGE((t + 1) * 64, bsel ^ 1); VLOAD((t + 1) * 64); }
    // --- QK^T swapped (this wave's 32 keys x its 32 q) ---
    f32x16 sc = {};
    __builtin_amdgcn_s_setprio(1);
    #pragma unroll
    for (int kc = 0; kc < 4; ++kc) {
      int st = (kc*2 + hi) ^ Sk;
      short8 kf = *(const short8*)(&Ks[bsel][krow*64 + st*8]);
      sc = __builtin_amdgcn_mfma_f32_32x32x16_bf16(kf, qf[kc], sc, 0, 0, 0);
    }
    __builtin_amdgcn_s_setprio(0);
    // --- no-max softmax: p = exp2(sc*CSC), L += sum ---
    float p[16]; float ls = 0.f;
    #pragma unroll
    for (int i = 0; i < 16; ++i) { p[i] = exp2f(sc[i]*CSC); ls += p[i]; }
    Lr += ls + __shfl_xor(ls, 32);
    // --- pack P -> PV A-frags ---
    union { int w[4]; short8 v; } pf0, pf1;
    int ta, tb;
    asm("v_cvt_pk_bf16_f32 %0, %1, %2" : "=v"(ta) : "v"(p[0]), "v"(p[1]));
    asm("v_cvt_pk_bf16_f32 %0, %1, %2" : "=v"(tb) : "v"(p[4]), "v"(p[5]));
    asm volatile("v_permlane32_swap_b32 %0, %1" : "+v"(ta), "+v"(tb));
    pf0.w[0] = ta; pf0.w[2] = tb;
    asm("v_cvt_pk_bf16_f32 %0, %1, %2" : "=v"(ta) : "v"(p[2]), "v"(p[3]));
    asm("v_cvt_pk_bf16_f32 %0, %1, %2" : "=v"(tb) : "v"(p[6]), "v"(p[7]));
    asm volatile("v_permlane32_swap_b32 %0, %1" : "+v"(ta), "+v"(tb));
    pf0.w[1] = ta; pf0.w[3] = tb;
    asm("v_cvt_pk_bf16_f32 %0, %1, %2" : "=v"(ta) : "v"(p[8]), "v"(p[9]));
    asm("v_cvt_pk_bf16_f32 %0, %1, %2" : "=v"(tb) : "v"(p[12]), "v"(p[13]));
    asm volatile("v_permlane32_swap_b32 %0, %1" : "+v"(ta), "+v"(tb));
    pf1.w[0] = ta; pf1.w[2] = tb;
    asm("v_cvt_pk_bf16_f32 %0, %1, %2" : "=v"(ta) : "v"(p[10]), "v"(p[11]));
    asm("v_cvt_pk_bf16_f32 %0, %1, %2" : "=v"(tb) : "v"(p[14]), "v"(p[15]));
    asm volatile("v_permlane32_swap_b32 %0, %1" : "+v"(ta), "+v"(tb));
    pf1.w[1] = ta; pf1.w[3] = tb;
    // --- PV over this wave's key half ---
    __builtin_amdgcn_s_setprio(1);
    #pragma unroll
    for (int kb = 0; kb < 2; ++kb) {
      const short8 pv = (kb == 0) ? pf0.v : pf1.v;
      #pragma unroll
      for (int hb = 0; hb < 2; ++hb) {
        int h = hb*32 + l31;
        int cc = (kh*4 + kb*2 + hi) ^ (((h >> 3) ^ h) & 7);
        short8 vf = *(const short8*)(&VTs[h*64 + cc*8]);
        if (hb == 0) o0 = __builtin_amdgcn_mfma_f32_32x32x16_bf16(pv, vf, o0, 0, 0, 0);
        else         o1 = __builtin_amdgcn_mfma_f32_32x32x16_bf16(pv, vf, o1, 0, 0, 0);
      }
    }
    __builtin_amdgcn_s_setprio(0);
    bsel ^= 1;
  }
  // --- cross-wave combine: (qw,kh=1) partials -> (qw,kh=0) waves ---
  __syncthreads();                           // all compute done; LDS reusable
  float* Ops = (float*)&Ks[0][0];            // [64][64] f32 = 16 KB
  float* Lp  = (float*)&VTs[0];              // [64] f32
  if (kh == 1) {
    #pragma unroll
    for (int reg = 0; reg < 16; ++reg) {
      int crow = (reg & 3) + 8*(reg >> 2) + 4*hi;
      Ops[(qw*32 + crow)*64 + l31]      = o0[reg];
      Ops[(qw*32 + crow)*64 + 32 + l31] = o1[reg];
    }
    if (lane < 32) Lp[qw*32 + lane] = Lr;
  }
  __syncthreads();
  if (kh == 0) {
    #pragma unroll
    for (int reg = 0; reg < 16; ++reg) {
      int crow = (reg & 3) + 8*(reg >> 2) + 4*hi;
      o0[reg] += Ops[(qw*32 + crow)*64 + l31];
      o1[reg] += Ops[(qw*32 + crow)*64 + 32 + l31];
    }
    if (lane < 32) {
      float Lt = Lr + Lp[qw*32 + lane];
      float g = gates[(size_t)(b*SEQ + s0 + qw*32 + lane) * NUM_EXPERTS + e];
      Ltab[qw*32 + lane] = g / Lt;
    }
    const int rowbase = b*SEQ + s0 + qw*32;
    #pragma unroll
    for (int reg = 0; reg < 16; ++reg) {
      int crow = (reg & 3) + 8*(reg >> 2) + 4*hi;
      float inv = Ltab[qw*32 + crow];
      combined[(size_t)(rowbase + crow)*D_MODEL + e*64 + l31] =
          __float2bfloat16(o0[reg] * inv);
      combined[(size_t)(rowbase + crow)*D_MODEL + e*64 + 32 + l31] =
          __float2bfloat16(o1[reg] * inv);
    }
  }
}

extern "C" void kernel_launch(void* const* d_in, const int* in_sizes, int n_in,
                              void* d_out, int out_size, void* d_ws, size_t ws_size,
                              hipStream_t stream) {
  const float* x    = (const float*)d_in[0];
  const float* wqkv = (const float*)d_in[1];
  const float* bqkv = (const float*)d_in[2];
  const float* rw   = (const float*)d_in[3];
  const float* rb   = (const float*)d_in[4];
  const float* ow   = (const float*)d_in[5];
  const float* ob   = (const float*)d_in[6];
  char* ws = (char*)d_ws;
  bf16*  xb    = (bf16*)(ws);                    // 4096*1280*2      = 10485760
  bf16*  wqkvT = (bf16*)(ws + 10485760);         // [3840][1280] bf16=  9830400
  bf16*  owT   = (bf16*)(ws + 20316160);         // 1280*1280*2     =  3276800
  float* gates = (float*)(ws + 23592960);        // 4096*20*4       =   327680
  bf16*  qkv   = (bf16*)(ws + 23920640);         // [4096][3840] bf16= 31457280
  bf16*  comb  = (bf16*)(ws + 55377920);         // 4096*1280*2     = 10485760
  float* rwT   = (float*)comb;                   // aliased, consumed pre-attn

  k_rwT<<<(D_MODEL * NUM_EXPERTS + 255) / 256, 256, 0, stream>>>(rw, rwT);
  k_gates<<<1024, 256, 0, stream>>>(x, rwT, rb, gates, xb);
  k_transpose2<<<dim3(40, 40, 21), dim3(32, 8), 0, stream>>>(wqkv, wqkvT, ow, owT);
  k_gemm256<<<240, 512, 0, stream>>>(xb, wqkvT, bqkv, qkv, BS_TOK, QKV_W, D_MODEL);
  k_attn<<<1280, 256, 0, stream>>>(qkv, gates, comb);
  k_gemm128r<<<320, 512, 0, stream>>>(comb, owT, ob, (float*)d_out,
                                      BS_TOK, D_MODEL, D_MODEL);
}